// Round 15
// baseline (1128.594 us; speedup 1.0000x reference)
//
#include <hip/hip_runtime.h>
#include <cstdint>
#include <cmath>

// Transformer encoder: B=256, L=100, D=512, F=2048, NL=4, H=8, hd=64.
// Round-15: round-14 + A-panel-affine XCD mapping in gemm128 (all bn-blocks of
// one bm-group run consecutively on one XCD -> A fetched once per chip).

#define NLAYERS 4
#define BB 256
#define LL 100
#define DD 512
#define FF 2048
#define NH 8
#define HD 64
#define MM (BB*LL)   // 25600 rows
#define ATT_R 112
#define ATT_K 128

typedef __bf16 bf16;
typedef bf16 bf16x8 __attribute__((ext_vector_type(8)));
typedef bf16 bf16x4 __attribute__((ext_vector_type(4)));
typedef float f32x4 __attribute__((ext_vector_type(4)));

__device__ __forceinline__ void load16(const void* g, void* l) {
  __builtin_amdgcn_global_load_lds(
      (const __attribute__((address_space(1))) void*)g,
      (__attribute__((address_space(3))) void*)l, 16, 0, 0);
}

// ---------------- positional encoding table [L][D] ----------------
__global__ void pe_kernel(float* __restrict__ pe) {
  const int idx = blockIdx.x * 256 + threadIdx.x;
  if (idx >= LL * DD) return;
  const int l = idx >> 9, d = idx & 511;
  const int i = d >> 1;
  const float div = expf((float)(2 * i) * (-9.210340371976184f / 512.f));
  const float ang = (float)l * div;
  pe[idx] = (d & 1) ? cosf(ang) : sinf(ang);
}

// ---------------- xb = bf16(2*x + pe) ----------------
__global__ __launch_bounds__(256) void x0_kernel(
    const float* __restrict__ xin, const float* __restrict__ pe,
    bf16* __restrict__ XB) {
  const size_t f = (size_t)blockIdx.x * 256 + threadIdx.x;
  const size_t e = f << 2;
  const int col  = (int)(e & 511);
  const int prow = (int)((e >> 9) % LL);
  const float4 xv = *(const float4*)(xin + e);
  const float4 pv = *(const float4*)(pe + (size_t)prow * DD + col);
  bf16x4 pk;
  pk[0] = (bf16)(2.f * xv.x + pv.x);
  pk[1] = (bf16)(2.f * xv.y + pv.y);
  pk[2] = (bf16)(2.f * xv.z + pv.z);
  pk[3] = (bf16)(2.f * xv.w + pv.w);
  *(bf16x4*)(XB + e) = pk;
}

// ---------------- weight cast + transpose: [K][N] f32 -> [N][K] bf16 ----------------
__global__ void transpose_cast(const float* __restrict__ src, bf16* __restrict__ dst,
                               int K, int N) {
  __shared__ float tile[32][33];
  const int z = blockIdx.z;
  src += (size_t)z * K * N;
  dst += (size_t)z * K * N;
  const int k0 = blockIdx.y * 32, n0 = blockIdx.x * 32;
  const int tx = threadIdx.x, ty = threadIdx.y;
  #pragma unroll
  for (int i = 0; i < 32; i += 8)
    tile[ty + i][tx] = src[(size_t)(k0 + ty + i) * N + n0 + tx];
  __syncthreads();
  #pragma unroll
  for (int i = 0; i < 32; i += 8)
    dst[(size_t)(n0 + ty + i) * K + k0 + tx] = (bf16)tile[tx][ty + i];
}

// ============ shared helpers (row*128B, 8 slots, XOR r&7 swizzle) ============
__device__ __forceinline__ bf16x8 lds_frag(const bf16* chunk, int lrow, int cb) {
  return *(const bf16x8*)(chunk + (lrow << 6) + ((cb ^ (lrow & 7)) << 3));
}

// ============ 128x128 BK=64 GEMM, 16x16x32 MFMA, 64KB LDS, 2 blocks/CU ============
__device__ __forceinline__ void stage4(const bf16* g, size_t r32, bf16* chunk, int w) {
  load16(g,            chunk + (w << 9));
  load16(g + r32,      chunk + 2048 + (w << 9));
  load16(g + 2 * r32,  chunk + 4096 + (w << 9));
  load16(g + 3 * r32,  chunk + 6144 + (w << 9));
}

template<int OUT_BF16, int RELU>
__global__ __launch_bounds__(256, 2) void gemm128(
    const bf16* __restrict__ A, const bf16* __restrict__ Bt,
    const float* __restrict__ bias, void* __restrict__ Cv,
    int N, int K) {
  __shared__ __align__(16) bf16 sA[2][128 * 64];
  __shared__ __align__(16) bf16 sB[2][128 * 64];
  const int tid = threadIdx.x;
  const int w = tid >> 6, lane = tid & 63;
  const int wr = w >> 1, wc = w & 1;
  const int lr16 = lane & 15, lg = lane >> 4;
  const int NT = K >> 6;

  // A-panel-affine XCD mapping: xcd = orig&7 (HW round-robin heuristic);
  // within an XCD walk bn fastest -> all bn-blocks of one bm-group land
  // consecutively on one XCD; each A-panel is owned by exactly one XCD.
  // Requires gridDim.y % 8 == 0 (we always launch y=200).
  const int C = gridDim.x;
  const int orig = blockIdx.y * C + blockIdx.x;
  const int xcd = orig & 7, j = orig >> 3;
  const int bn = (j % C) << 7;
  const int bm = (xcd + 8 * (j / C)) << 7;

  const int rr0 = tid >> 3;
  const int cb  = (tid & 7) ^ (rr0 & 7);
  const bf16* gA = A  + (size_t)(bm + rr0) * K + (cb << 3);
  const bf16* gB = Bt + (size_t)(bn + rr0) * K + (cb << 3);
  const size_t r32 = (size_t)32 * K;

  f32x4 acc[4][4] = {};
  bf16x8 Af[4][2], Bf[4][2];

  stage4(gA,      r32, sA[0], w);
  stage4(gB,      r32, sB[0], w);
  stage4(gA + 64, r32, sA[1], w);
  stage4(gB + 64, r32, sB[1], w);

  for (int t = 0; t < NT; ++t) {
    const int cur = t & 1;
    if (t < NT - 1) asm volatile("s_waitcnt vmcnt(8)" ::: "memory");
    else            asm volatile("s_waitcnt vmcnt(0)" ::: "memory");
    __builtin_amdgcn_s_barrier();

    #pragma unroll
    for (int m = 0; m < 4; ++m) {
      const int lrow = wr * 64 + m * 16 + lr16;
      Af[m][0] = lds_frag(sA[cur], lrow, lg);
      Af[m][1] = lds_frag(sA[cur], lrow, 4 + lg);
    }
    #pragma unroll
    for (int n = 0; n < 4; ++n) {
      const int lrow = wc * 64 + n * 16 + lr16;
      Bf[n][0] = lds_frag(sB[cur], lrow, lg);
      Bf[n][1] = lds_frag(sB[cur], lrow, 4 + lg);
    }
    __builtin_amdgcn_s_barrier();        // all reads issued; cur safe to restage

    if (t + 2 < NT) stage4(gA + (size_t)(t + 2) * 64, r32, sA[cur], w);
    __builtin_amdgcn_s_setprio(1);
    #pragma unroll
    for (int m = 0; m < 4; ++m)
      #pragma unroll
      for (int n = 0; n < 4; ++n)
        acc[m][n] = __builtin_amdgcn_mfma_f32_16x16x32_bf16(Af[m][0], Bf[n][0], acc[m][n], 0, 0, 0);
    __builtin_amdgcn_s_setprio(0);
    if (t + 2 < NT) stage4(gB + (size_t)(t + 2) * 64, r32, sB[cur], w);
    __builtin_amdgcn_s_setprio(1);
    #pragma unroll
    for (int m = 0; m < 4; ++m)
      #pragma unroll
      for (int n = 0; n < 4; ++n)
        acc[m][n] = __builtin_amdgcn_mfma_f32_16x16x32_bf16(Af[m][1], Bf[n][1], acc[m][n], 0, 0, 0);
    __builtin_amdgcn_s_setprio(0);
  }

  const int g4 = (lane >> 4) << 2;
  #pragma unroll
  for (int n = 0; n < 4; ++n) {
    const int col = bn + wc * 64 + n * 16 + lr16;
    const float bvv = bias ? bias[col] : 0.f;
    #pragma unroll
    for (int m = 0; m < 4; ++m) {
      const int row = bm + wr * 64 + m * 16 + g4;
      #pragma unroll
      for (int j2 = 0; j2 < 4; ++j2) {
        float v = acc[m][n][j2] + bvv;
        if (RELU) v = fmaxf(v, 0.f);
        if (OUT_BF16) ((bf16*)Cv)[(size_t)(row + j2) * N + col] = (bf16)v;
        else          ((float*)Cv)[(size_t)(row + j2) * N + col] = v;
      }
    }
  }
}

// ---------------- MFMA attention: one block (4 waves) per (b,h) ----------------
// Prologue-trimmed: only V pad cols (100-135) pre-zeroed; P pad cols 112-127
// zeroed during phase 1; Q/K pad rows left as garbage (contained).
__global__ __launch_bounds__(256) void attn_mfma(
    const bf16* __restrict__ qkv, const int* __restrict__ mask,
    bf16* __restrict__ aout) {
  __shared__ __align__(16) bf16 sQ[ATT_R * 64];
  __shared__ __align__(16) bf16 sK[ATT_R * 64];
  __shared__ __align__(16) bf16 sVt[64 * 136];
  __shared__ __align__(16) bf16 sP[ATT_R * ATT_K];
  __shared__ int sM[ATT_R];
  const int bh = blockIdx.x, b = bh >> 3, h = bh & 7;
  const int tid = threadIdx.x, w = tid >> 6, lane = tid & 63;
  const int lr = lane & 15;
  const int lk = (lane >> 4) << 3;
  const int g  = lane >> 4;

  // zero sVt cols 100-135 only (row stride 272B; col100 = byte 200)
  for (int i = tid; i < 64 * 5; i += 256) {
    const int d = i / 5, c = i % 5;
    char* p = (char*)sVt + d * 272 + 200;
    if (c == 0) { *(int*)p = 0; *(int*)(p + 4) = 0; }
    else        *(int4*)(p + 8 + (c - 1) * 16) = int4{0,0,0,0};
  }

  const bf16* base = qkv + (size_t)(b * LL) * (3 * DD) + h * HD;
  for (int c = tid; c < LL * 8; c += 256) {
    const int l = c >> 3, u = c & 7;
    const bf16x8 qv = *(const bf16x8*)(base + (size_t)l * (3 * DD) + u * 8);
    const bf16x8 kv = *(const bf16x8*)(base + (size_t)l * (3 * DD) + DD + u * 8);
    const bf16x8 vv = *(const bf16x8*)(base + (size_t)l * (3 * DD) + 2 * DD + u * 8);
    const int qb = (l * 128 + u * 16) ^ ((l & 7) << 4);
    *(bf16x8*)((char*)sQ + qb) = qv;
    *(bf16x8*)((char*)sK + qb) = kv;
    #pragma unroll
    for (int j = 0; j < 8; ++j) sVt[(u * 8 + j) * 136 + l] = vv[j];
  }
  if (tid < ATT_R) sM[tid] = (tid < LL) ? mask[b * LL + tid] : 0;
  __syncthreads();

  #pragma unroll
  for (int fi = 0; fi < 2; ++fi) {
    const int fm = w + fi * 4;
    if (fm >= 7) continue;
    const int ar = fm * 16 + lr;
    const int abase = ar * 128;
    const int aswz = (ar & 7) << 4;
    const bf16x8 a0 = *(const bf16x8*)((char*)sQ + ((abase + lk * 2) ^ aswz));
    const bf16x8 a1 = *(const bf16x8*)((char*)sQ + ((abase + 64 + lk * 2) ^ aswz));
    f32x4 s[7];
    #pragma unroll
    for (int fn = 0; fn < 7; ++fn) {
      const int br = fn * 16 + lr;
      const int bswz = (br & 7) << 4;
      const bf16x8 b0 = *(const bf16x8*)((char*)sK + ((br * 128 + lk * 2) ^ bswz));
      const bf16x8 b1 = *(const bf16x8*)((char*)sK + ((br * 128 + 64 + lk * 2) ^ bswz));
      f32x4 acc = {};
      acc = __builtin_amdgcn_mfma_f32_16x16x32_bf16(a0, b0, acc, 0, 0, 0);
      acc = __builtin_amdgcn_mfma_f32_16x16x32_bf16(a1, b1, acc, 0, 0, 0);
      s[fn] = acc;
    }
    #pragma unroll
    for (int fn = 0; fn < 7; ++fn) {
      if (sM[fn * 16 + lr] == 0) {
        s[fn][0] = -INFINITY; s[fn][1] = -INFINITY;
        s[fn][2] = -INFINITY; s[fn][3] = -INFINITY;
      }
    }
    float sm[4];
    #pragma unroll
    for (int j = 0; j < 4; ++j) {
      float m = s[0][j];
      #pragma unroll
      for (int fn = 1; fn < 7; ++fn) m = fmaxf(m, s[fn][j]);
      #pragma unroll
      for (int off = 1; off < 16; off <<= 1) m = fmaxf(m, __shfl_xor(m, off, 64));
      float t = 0.f;
      #pragma unroll
      for (int fn = 0; fn < 7; ++fn) { const float p = __expf(s[fn][j] - m); s[fn][j] = p; t += p; }
      #pragma unroll
      for (int off = 1; off < 16; off <<= 1) t += __shfl_xor(t, off, 64);
      sm[j] = 1.f / t;
    }
    #pragma unroll
    for (int fn = 0; fn < 7; ++fn) {
      const int k = fn * 16 + lr;
      #pragma unroll
      for (int j = 0; j < 4; ++j) {
        const int rr = fm * 16 + 4 * g + j;
        const int byte = (rr * 256 + k * 2) ^ ((rr & 7) << 4);
        *(bf16*)((char*)sP + byte) = (bf16)(s[fn][j] * sm[j]);
      }
    }
    {
      const int kz = 112 + lr;
      #pragma unroll
      for (int j = 0; j < 4; ++j) {
        const int rr = fm * 16 + 4 * g + j;
        const int byte = (rr * 256 + kz * 2) ^ ((rr & 7) << 4);
        *(bf16*)((char*)sP + byte) = (bf16)0.f;
      }
    }
  }
  __syncthreads();

  bf16x8 bV[4];
  #pragma unroll
  for (int ks = 0; ks < 4; ++ks)
    bV[ks] = *(const bf16x8*)((char*)sVt + ((w * 16 + lr) * 272 + ks * 64 + lk * 2));
  #pragma unroll
  for (int fm = 0; fm < 7; ++fm) {
    f32x4 acc = {};
    const int ar = fm * 16 + lr;
    const int aswz = (ar & 7) << 4;
    #pragma unroll
    for (int ks = 0; ks < 4; ++ks) {
      const bf16x8 aP = *(const bf16x8*)((char*)sP + ((ar * 256 + ks * 64 + lk * 2) ^ aswz));
      acc = __builtin_amdgcn_mfma_f32_16x16x32_bf16(aP, bV[ks], acc, 0, 0, 0);
    }
    const int d = h * HD + w * 16 + lr;
    #pragma unroll
    for (int j = 0; j < 4; ++j) {
      const int qr = fm * 16 + 4 * g + j;
      if (qr < LL) aout[(size_t)(b * LL + qr) * DD + d] = (bf16)acc[j];
    }
  }
}

// ---------------- residual add + LayerNorm (4 waves x 4 rows per block) ----------
template<int WRITE_F32>
__global__ __launch_bounds__(256) void ln_kernel(
    const float* __restrict__ Y, const bf16* __restrict__ RES,
    const float* __restrict__ g, const float* __restrict__ bt,
    bf16* __restrict__ XB, float* __restrict__ XF) {
  const int row = blockIdx.x * 4 + (threadIdx.x >> 6);
  const int lane = threadIdx.x & 63;
  const size_t base = (size_t)row * DD + lane * 8;
  const float4 a0 = *(const float4*)(Y + base);
  const float4 a1 = *(const float4*)(Y + base + 4);
  const bf16x8 rv = *(const bf16x8*)(RES + base);
  float z[8];
  z[0] = a0.x + (float)rv[0]; z[1] = a0.y + (float)rv[1];
  z[2] = a0.z + (float)rv[2]; z[3] = a0.w + (float)rv[3];
  z[4] = a1.x + (float)rv[4]; z[5] = a1.y + (float)rv[5];
  z[6] = a1.z + (float)rv[6]; z[7] = a1.w + (float)rv[7];
  float s = 0.f, s2 = 0.f;
  #pragma unroll
  for (int j = 0; j < 8; ++j) { s += z[j]; s2 = fmaf(z[j], z[j], s2); }
  #pragma unroll
  for (int off = 32; off > 0; off >>= 1) {
    s  += __shfl_xor(s, off, 64);
    s2 += __shfl_xor(s2, off, 64);
  }
  const float mu = s * (1.f / 512.f);
  const float var = s2 * (1.f / 512.f) - mu * mu;
  const float inv = rsqrtf(var + 1e-5f);
  const int c = lane * 8;
  const float4 g0 = *(const float4*)(g + c),  g1 = *(const float4*)(g + c + 4);
  const float4 b0 = *(const float4*)(bt + c), b1 = *(const float4*)(bt + c + 4);
  float ov[8];
  ov[0] = (z[0] - mu) * inv * g0.x + b0.x; ov[1] = (z[1] - mu) * inv * g0.y + b0.y;
  ov[2] = (z[2] - mu) * inv * g0.z + b0.z; ov[3] = (z[3] - mu) * inv * g0.w + b0.w;
  ov[4] = (z[4] - mu) * inv * g1.x + b1.x; ov[5] = (z[5] - mu) * inv * g1.y + b1.y;
  ov[6] = (z[6] - mu) * inv * g1.z + b1.z; ov[7] = (z[7] - mu) * inv * g1.w + b1.w;
  bf16x8 pk;
  #pragma unroll
  for (int j = 0; j < 8; ++j) pk[j] = (bf16)ov[j];
  *(bf16x8*)(XB + base) = pk;
  if (WRITE_F32) {
    *(float4*)(XF + base)     = make_float4(ov[0], ov[1], ov[2], ov[3]);
    *(float4*)(XF + base + 4) = make_float4(ov[4], ov[5], ov[6], ov[7]);
  }
}

extern "C" void kernel_launch(void* const* d_in, const int* in_sizes, int n_in,
                              void* d_out, int out_size, void* d_ws, size_t ws_size,
                              hipStream_t stream) {
  const float* x_in   = (const float*)d_in[0];
  const int*   mask   = (const int*)d_in[1];
  const float* qkv_w  = (const float*)d_in[2];
  const float* fc_w   = (const float*)d_in[3];
  const float* fc_b   = (const float*)d_in[4];
  const float* ln1_g  = (const float*)d_in[5];
  const float* ln1_b  = (const float*)d_in[6];
  const float* ln2_g  = (const float*)d_in[7];
  const float* ln2_b  = (const float*)d_in[8];
  const float* ffn_w1 = (const float*)d_in[9];
  const float* ffn_b1 = (const float*)d_in[10];
  const float* ffn_w2 = (const float*)d_in[11];
  const float* ffn_b2 = (const float*)d_in[12];

  char* ws = (char*)d_ws;
  size_t off = 0;
  auto alloc = [&](size_t bytes) -> void* {
    off = (off + 255) & ~(size_t)255;
    void* p = ws + off;
    off += bytes;
    return p;
  };
  bf16*  XB   = (bf16*) alloc((size_t)MM * DD * 2);
  bf16*  BIGB = (bf16*) alloc((size_t)MM * FF * 2);
  float* PE   = (float*)alloc((size_t)LL * DD * 4);
  bf16*  WQKV = (bf16*) alloc((size_t)NLAYERS * DD * 3 * DD * 2);
  bf16*  WFC  = (bf16*) alloc((size_t)NLAYERS * DD * DD * 2);
  bf16*  W1T  = (bf16*) alloc((size_t)NLAYERS * DD * FF * 2);
  bf16*  W2T  = (bf16*) alloc((size_t)NLAYERS * FF * DD * 2);
  bf16*  AOUT = BIGB + (size_t)MM * (3 * DD);
  float* Y    = (float*)d_out;
  (void)ws_size; (void)in_sizes; (void)n_in; (void)out_size;

  pe_kernel<<<200, 256, 0, stream>>>(PE);
  transpose_cast<<<dim3(48, 16, NLAYERS), dim3(32, 8), 0, stream>>>(qkv_w,  WQKV, 512, 1536);
  transpose_cast<<<dim3(16, 16, NLAYERS), dim3(32, 8), 0, stream>>>(fc_w,   WFC,  512, 512);
  transpose_cast<<<dim3(64, 16, NLAYERS), dim3(32, 8), 0, stream>>>(ffn_w1, W1T,  512, 2048);
  transpose_cast<<<dim3(16, 64, NLAYERS), dim3(32, 8), 0, stream>>>(ffn_w2, W2T,  2048, 512);
  x0_kernel<<<12800, 256, 0, stream>>>(x_in, PE, XB);

  for (int i = 0; i < NLAYERS; ++i) {
    // qkv = x @ qkv_w -> bf16 [M,1536]
    gemm128<1, 0><<<dim3(12, 200), 256, 0, stream>>>(
        XB, WQKV + (size_t)i * DD * 3 * DD, nullptr, BIGB, 3 * DD, DD);
    attn_mfma<<<BB * NH, 256, 0, stream>>>(BIGB, mask, AOUT);
    // attn proj + bias -> fp32 Y
    gemm128<0, 0><<<dim3(4, 200), 256, 0, stream>>>(
        AOUT, WFC + (size_t)i * DD * DD, fc_b + i * DD, Y, DD, DD);
    // x = LN(Y + x)
    ln_kernel<0><<<MM / 4, 256, 0, stream>>>(Y, XB, ln1_g + i * DD, ln1_b + i * DD, XB, nullptr);
    // h = relu(x @ w1 + b1) -> bf16 [M,2048]
    gemm128<1, 1><<<dim3(16, 200), 256, 0, stream>>>(
        XB, W1T + (size_t)i * DD * FF, ffn_b1 + i * FF, BIGB, FF, DD);
    // y = h @ w2 + b2 -> fp32 Y
    gemm128<0, 0><<<dim3(4, 200), 256, 0, stream>>>(
        BIGB, W2T + (size_t)i * FF * DD, ffn_b2 + i * DD, Y, DD, FF);
    // x = LN(Y + x); final layer also writes fp32 d_out (in place on Y rows)
    if (i == NLAYERS - 1)
      ln_kernel<1><<<MM / 4, 256, 0, stream>>>(Y, XB, ln2_g + i * DD, ln2_b + i * DD,
                                               XB, (float*)d_out);
    else
      ln_kernel<0><<<MM / 4, 256, 0, stream>>>(Y, XB, ln2_g + i * DD, ln2_b + i * DD, XB, nullptr);
  }
}

// Round 16
// 1116.904 us; speedup vs baseline: 1.0105x; 1.0105x over previous
//
#include <hip/hip_runtime.h>
#include <cstdint>
#include <cmath>

// Transformer encoder: B=256, L=100, D=512, F=2048, NL=4, H=8, hd=64.
// Round-16: exact revert to round-14 champion (1119.9 us): all GEMMs
// gemm128 BK=64 16x16x32 (2 blocks/CU, generic XCD swizzle), separate LN,
// prologue-trimmed attn.

#define NLAYERS 4
#define BB 256
#define LL 100
#define DD 512
#define FF 2048
#define NH 8
#define HD 64
#define MM (BB*LL)   // 25600 rows
#define ATT_R 112
#define ATT_K 128

typedef __bf16 bf16;
typedef bf16 bf16x8 __attribute__((ext_vector_type(8)));
typedef bf16 bf16x4 __attribute__((ext_vector_type(4)));
typedef float f32x4 __attribute__((ext_vector_type(4)));

__device__ __forceinline__ void load16(const void* g, void* l) {
  __builtin_amdgcn_global_load_lds(
      (const __attribute__((address_space(1))) void*)g,
      (__attribute__((address_space(3))) void*)l, 16, 0, 0);
}

// ---------------- positional encoding table [L][D] ----------------
__global__ void pe_kernel(float* __restrict__ pe) {
  const int idx = blockIdx.x * 256 + threadIdx.x;
  if (idx >= LL * DD) return;
  const int l = idx >> 9, d = idx & 511;
  const int i = d >> 1;
  const float div = expf((float)(2 * i) * (-9.210340371976184f / 512.f));
  const float ang = (float)l * div;
  pe[idx] = (d & 1) ? cosf(ang) : sinf(ang);
}

// ---------------- xb = bf16(2*x + pe) ----------------
__global__ __launch_bounds__(256) void x0_kernel(
    const float* __restrict__ xin, const float* __restrict__ pe,
    bf16* __restrict__ XB) {
  const size_t f = (size_t)blockIdx.x * 256 + threadIdx.x;
  const size_t e = f << 2;
  const int col  = (int)(e & 511);
  const int prow = (int)((e >> 9) % LL);
  const float4 xv = *(const float4*)(xin + e);
  const float4 pv = *(const float4*)(pe + (size_t)prow * DD + col);
  bf16x4 pk;
  pk[0] = (bf16)(2.f * xv.x + pv.x);
  pk[1] = (bf16)(2.f * xv.y + pv.y);
  pk[2] = (bf16)(2.f * xv.z + pv.z);
  pk[3] = (bf16)(2.f * xv.w + pv.w);
  *(bf16x4*)(XB + e) = pk;
}

// ---------------- weight cast + transpose: [K][N] f32 -> [N][K] bf16 ----------------
__global__ void transpose_cast(const float* __restrict__ src, bf16* __restrict__ dst,
                               int K, int N) {
  __shared__ float tile[32][33];
  const int z = blockIdx.z;
  src += (size_t)z * K * N;
  dst += (size_t)z * K * N;
  const int k0 = blockIdx.y * 32, n0 = blockIdx.x * 32;
  const int tx = threadIdx.x, ty = threadIdx.y;
  #pragma unroll
  for (int i = 0; i < 32; i += 8)
    tile[ty + i][tx] = src[(size_t)(k0 + ty + i) * N + n0 + tx];
  __syncthreads();
  #pragma unroll
  for (int i = 0; i < 32; i += 8)
    dst[(size_t)(n0 + ty + i) * K + k0 + tx] = (bf16)tile[tx][ty + i];
}

// ============ shared helpers (row*128B, 8 slots, XOR r&7 swizzle) ============
__device__ __forceinline__ bf16x8 lds_frag(const bf16* chunk, int lrow, int cb) {
  return *(const bf16x8*)(chunk + (lrow << 6) + ((cb ^ (lrow & 7)) << 3));
}

// ============ 128x128 BK=64 GEMM, 16x16x32 MFMA, 64KB LDS, 2 blocks/CU ============
__device__ __forceinline__ void stage4(const bf16* g, size_t r32, bf16* chunk, int w) {
  load16(g,            chunk + (w << 9));
  load16(g + r32,      chunk + 2048 + (w << 9));
  load16(g + 2 * r32,  chunk + 4096 + (w << 9));
  load16(g + 3 * r32,  chunk + 6144 + (w << 9));
}

template<int OUT_BF16, int RELU>
__global__ __launch_bounds__(256, 2) void gemm128(
    const bf16* __restrict__ A, const bf16* __restrict__ Bt,
    const float* __restrict__ bias, void* __restrict__ Cv,
    int N, int K) {
  __shared__ __align__(16) bf16 sA[2][128 * 64];
  __shared__ __align__(16) bf16 sB[2][128 * 64];
  const int tid = threadIdx.x;
  const int w = tid >> 6, lane = tid & 63;
  const int wr = w >> 1, wc = w & 1;
  const int lr16 = lane & 15, lg = lane >> 4;
  const int NT = K >> 6;

  const int nwg = gridDim.x * gridDim.y;
  const int orig = blockIdx.y * gridDim.x + blockIdx.x;
  const int q = nwg >> 3, r = nwg & 7;
  const int xcd = orig & 7, lo = orig >> 3;
  const int swz = (xcd < r ? xcd * (q + 1) : r * (q + 1) + (xcd - r) * q) + lo;
  const int bn = (swz % gridDim.x) << 7;
  const int bm = (swz / gridDim.x) << 7;

  const int rr0 = tid >> 3;
  const int cb  = (tid & 7) ^ (rr0 & 7);
  const bf16* gA = A  + (size_t)(bm + rr0) * K + (cb << 3);
  const bf16* gB = Bt + (size_t)(bn + rr0) * K + (cb << 3);
  const size_t r32 = (size_t)32 * K;

  f32x4 acc[4][4] = {};
  bf16x8 Af[4][2], Bf[4][2];

  stage4(gA,      r32, sA[0], w);
  stage4(gB,      r32, sB[0], w);
  stage4(gA + 64, r32, sA[1], w);
  stage4(gB + 64, r32, sB[1], w);

  for (int t = 0; t < NT; ++t) {
    const int cur = t & 1;
    if (t < NT - 1) asm volatile("s_waitcnt vmcnt(8)" ::: "memory");
    else            asm volatile("s_waitcnt vmcnt(0)" ::: "memory");
    __builtin_amdgcn_s_barrier();

    #pragma unroll
    for (int m = 0; m < 4; ++m) {
      const int lrow = wr * 64 + m * 16 + lr16;
      Af[m][0] = lds_frag(sA[cur], lrow, lg);
      Af[m][1] = lds_frag(sA[cur], lrow, 4 + lg);
    }
    #pragma unroll
    for (int n = 0; n < 4; ++n) {
      const int lrow = wc * 64 + n * 16 + lr16;
      Bf[n][0] = lds_frag(sB[cur], lrow, lg);
      Bf[n][1] = lds_frag(sB[cur], lrow, 4 + lg);
    }
    __builtin_amdgcn_s_barrier();        // all reads issued; cur safe to restage

    if (t + 2 < NT) stage4(gA + (size_t)(t + 2) * 64, r32, sA[cur], w);
    __builtin_amdgcn_s_setprio(1);
    #pragma unroll
    for (int m = 0; m < 4; ++m)
      #pragma unroll
      for (int n = 0; n < 4; ++n)
        acc[m][n] = __builtin_amdgcn_mfma_f32_16x16x32_bf16(Af[m][0], Bf[n][0], acc[m][n], 0, 0, 0);
    __builtin_amdgcn_s_setprio(0);
    if (t + 2 < NT) stage4(gB + (size_t)(t + 2) * 64, r32, sB[cur], w);
    __builtin_amdgcn_s_setprio(1);
    #pragma unroll
    for (int m = 0; m < 4; ++m)
      #pragma unroll
      for (int n = 0; n < 4; ++n)
        acc[m][n] = __builtin_amdgcn_mfma_f32_16x16x32_bf16(Af[m][1], Bf[n][1], acc[m][n], 0, 0, 0);
    __builtin_amdgcn_s_setprio(0);
  }

  const int g4 = (lane >> 4) << 2;
  #pragma unroll
  for (int n = 0; n < 4; ++n) {
    const int col = bn + wc * 64 + n * 16 + lr16;
    const float bvv = bias ? bias[col] : 0.f;
    #pragma unroll
    for (int m = 0; m < 4; ++m) {
      const int row = bm + wr * 64 + m * 16 + g4;
      #pragma unroll
      for (int j = 0; j < 4; ++j) {
        float v = acc[m][n][j] + bvv;
        if (RELU) v = fmaxf(v, 0.f);
        if (OUT_BF16) ((bf16*)Cv)[(size_t)(row + j) * N + col] = (bf16)v;
        else          ((float*)Cv)[(size_t)(row + j) * N + col] = v;
      }
    }
  }
}

// ---------------- MFMA attention: one block (4 waves) per (b,h) ----------------
// Prologue-trimmed: only V pad cols (100-135) pre-zeroed; P pad cols 112-127
// zeroed during phase 1; Q/K pad rows left as garbage (contained).
__global__ __launch_bounds__(256) void attn_mfma(
    const bf16* __restrict__ qkv, const int* __restrict__ mask,
    bf16* __restrict__ aout) {
  __shared__ __align__(16) bf16 sQ[ATT_R * 64];
  __shared__ __align__(16) bf16 sK[ATT_R * 64];
  __shared__ __align__(16) bf16 sVt[64 * 136];
  __shared__ __align__(16) bf16 sP[ATT_R * ATT_K];
  __shared__ int sM[ATT_R];
  const int bh = blockIdx.x, b = bh >> 3, h = bh & 7;
  const int tid = threadIdx.x, w = tid >> 6, lane = tid & 63;
  const int lr = lane & 15;
  const int lk = (lane >> 4) << 3;
  const int g  = lane >> 4;

  // zero sVt cols 100-135 only (row stride 272B; col100 = byte 200)
  for (int i = tid; i < 64 * 5; i += 256) {
    const int d = i / 5, c = i % 5;
    char* p = (char*)sVt + d * 272 + 200;
    if (c == 0) { *(int*)p = 0; *(int*)(p + 4) = 0; }
    else        *(int4*)(p + 8 + (c - 1) * 16) = int4{0,0,0,0};
  }

  const bf16* base = qkv + (size_t)(b * LL) * (3 * DD) + h * HD;
  for (int c = tid; c < LL * 8; c += 256) {
    const int l = c >> 3, u = c & 7;
    const bf16x8 qv = *(const bf16x8*)(base + (size_t)l * (3 * DD) + u * 8);
    const bf16x8 kv = *(const bf16x8*)(base + (size_t)l * (3 * DD) + DD + u * 8);
    const bf16x8 vv = *(const bf16x8*)(base + (size_t)l * (3 * DD) + 2 * DD + u * 8);
    const int qb = (l * 128 + u * 16) ^ ((l & 7) << 4);
    *(bf16x8*)((char*)sQ + qb) = qv;
    *(bf16x8*)((char*)sK + qb) = kv;
    #pragma unroll
    for (int j = 0; j < 8; ++j) sVt[(u * 8 + j) * 136 + l] = vv[j];
  }
  if (tid < ATT_R) sM[tid] = (tid < LL) ? mask[b * LL + tid] : 0;
  __syncthreads();

  #pragma unroll
  for (int fi = 0; fi < 2; ++fi) {
    const int fm = w + fi * 4;
    if (fm >= 7) continue;
    const int ar = fm * 16 + lr;
    const int abase = ar * 128;
    const int aswz = (ar & 7) << 4;
    const bf16x8 a0 = *(const bf16x8*)((char*)sQ + ((abase + lk * 2) ^ aswz));
    const bf16x8 a1 = *(const bf16x8*)((char*)sQ + ((abase + 64 + lk * 2) ^ aswz));
    f32x4 s[7];
    #pragma unroll
    for (int fn = 0; fn < 7; ++fn) {
      const int br = fn * 16 + lr;
      const int bswz = (br & 7) << 4;
      const bf16x8 b0 = *(const bf16x8*)((char*)sK + ((br * 128 + lk * 2) ^ bswz));
      const bf16x8 b1 = *(const bf16x8*)((char*)sK + ((br * 128 + 64 + lk * 2) ^ bswz));
      f32x4 acc = {};
      acc = __builtin_amdgcn_mfma_f32_16x16x32_bf16(a0, b0, acc, 0, 0, 0);
      acc = __builtin_amdgcn_mfma_f32_16x16x32_bf16(a1, b1, acc, 0, 0, 0);
      s[fn] = acc;
    }
    #pragma unroll
    for (int fn = 0; fn < 7; ++fn) {
      if (sM[fn * 16 + lr] == 0) {
        s[fn][0] = -INFINITY; s[fn][1] = -INFINITY;
        s[fn][2] = -INFINITY; s[fn][3] = -INFINITY;
      }
    }
    float sm[4];
    #pragma unroll
    for (int j = 0; j < 4; ++j) {
      float m = s[0][j];
      #pragma unroll
      for (int fn = 1; fn < 7; ++fn) m = fmaxf(m, s[fn][j]);
      #pragma unroll
      for (int off = 1; off < 16; off <<= 1) m = fmaxf(m, __shfl_xor(m, off, 64));
      float t = 0.f;
      #pragma unroll
      for (int fn = 0; fn < 7; ++fn) { const float p = __expf(s[fn][j] - m); s[fn][j] = p; t += p; }
      #pragma unroll
      for (int off = 1; off < 16; off <<= 1) t += __shfl_xor(t, off, 64);
      sm[j] = 1.f / t;
    }
    #pragma unroll
    for (int fn = 0; fn < 7; ++fn) {
      const int k = fn * 16 + lr;
      #pragma unroll
      for (int j = 0; j < 4; ++j) {
        const int rr = fm * 16 + 4 * g + j;
        const int byte = (rr * 256 + k * 2) ^ ((rr & 7) << 4);
        *(bf16*)((char*)sP + byte) = (bf16)(s[fn][j] * sm[j]);
      }
    }
    {
      const int kz = 112 + lr;
      #pragma unroll
      for (int j = 0; j < 4; ++j) {
        const int rr = fm * 16 + 4 * g + j;
        const int byte = (rr * 256 + kz * 2) ^ ((rr & 7) << 4);
        *(bf16*)((char*)sP + byte) = (bf16)0.f;
      }
    }
  }
  __syncthreads();

  bf16x8 bV[4];
  #pragma unroll
  for (int ks = 0; ks < 4; ++ks)
    bV[ks] = *(const bf16x8*)((char*)sVt + ((w * 16 + lr) * 272 + ks * 64 + lk * 2));
  #pragma unroll
  for (int fm = 0; fm < 7; ++fm) {
    f32x4 acc = {};
    const int ar = fm * 16 + lr;
    const int aswz = (ar & 7) << 4;
    #pragma unroll
    for (int ks = 0; ks < 4; ++ks) {
      const bf16x8 aP = *(const bf16x8*)((char*)sP + ((ar * 256 + ks * 64 + lk * 2) ^ aswz));
      acc = __builtin_amdgcn_mfma_f32_16x16x32_bf16(aP, bV[ks], acc, 0, 0, 0);
    }
    const int d = h * HD + w * 16 + lr;
    #pragma unroll
    for (int j = 0; j < 4; ++j) {
      const int qr = fm * 16 + 4 * g + j;
      if (qr < LL) aout[(size_t)(b * LL + qr) * DD + d] = (bf16)acc[j];
    }
  }
}

// ---------------- residual add + LayerNorm (4 waves x 4 rows per block) ----------
template<int WRITE_F32>
__global__ __launch_bounds__(256) void ln_kernel(
    const float* __restrict__ Y, const bf16* __restrict__ RES,
    const float* __restrict__ g, const float* __restrict__ bt,
    bf16* __restrict__ XB, float* __restrict__ XF) {
  const int row = blockIdx.x * 4 + (threadIdx.x >> 6);
  const int lane = threadIdx.x & 63;
  const size_t base = (size_t)row * DD + lane * 8;
  const float4 a0 = *(const float4*)(Y + base);
  const float4 a1 = *(const float4*)(Y + base + 4);
  const bf16x8 rv = *(const bf16x8*)(RES + base);
  float z[8];
  z[0] = a0.x + (float)rv[0]; z[1] = a0.y + (float)rv[1];
  z[2] = a0.z + (float)rv[2]; z[3] = a0.w + (float)rv[3];
  z[4] = a1.x + (float)rv[4]; z[5] = a1.y + (float)rv[5];
  z[6] = a1.z + (float)rv[6]; z[7] = a1.w + (float)rv[7];
  float s = 0.f, s2 = 0.f;
  #pragma unroll
  for (int j = 0; j < 8; ++j) { s += z[j]; s2 = fmaf(z[j], z[j], s2); }
  #pragma unroll
  for (int off = 32; off > 0; off >>= 1) {
    s  += __shfl_xor(s, off, 64);
    s2 += __shfl_xor(s2, off, 64);
  }
  const float mu = s * (1.f / 512.f);
  const float var = s2 * (1.f / 512.f) - mu * mu;
  const float inv = rsqrtf(var + 1e-5f);
  const int c = lane * 8;
  const float4 g0 = *(const float4*)(g + c),  g1 = *(const float4*)(g + c + 4);
  const float4 b0 = *(const float4*)(bt + c), b1 = *(const float4*)(bt + c + 4);
  float ov[8];
  ov[0] = (z[0] - mu) * inv * g0.x + b0.x; ov[1] = (z[1] - mu) * inv * g0.y + b0.y;
  ov[2] = (z[2] - mu) * inv * g0.z + b0.z; ov[3] = (z[3] - mu) * inv * g0.w + b0.w;
  ov[4] = (z[4] - mu) * inv * g1.x + b1.x; ov[5] = (z[5] - mu) * inv * g1.y + b1.y;
  ov[6] = (z[6] - mu) * inv * g1.z + b1.z; ov[7] = (z[7] - mu) * inv * g1.w + b1.w;
  bf16x8 pk;
  #pragma unroll
  for (int j = 0; j < 8; ++j) pk[j] = (bf16)ov[j];
  *(bf16x8*)(XB + base) = pk;
  if (WRITE_F32) {
    *(float4*)(XF + base)     = make_float4(ov[0], ov[1], ov[2], ov[3]);
    *(float4*)(XF + base + 4) = make_float4(ov[4], ov[5], ov[6], ov[7]);
  }
}

extern "C" void kernel_launch(void* const* d_in, const int* in_sizes, int n_in,
                              void* d_out, int out_size, void* d_ws, size_t ws_size,
                              hipStream_t stream) {
  const float* x_in   = (const float*)d_in[0];
  const int*   mask   = (const int*)d_in[1];
  const float* qkv_w  = (const float*)d_in[2];
  const float* fc_w   = (const float*)d_in[3];
  const float* fc_b   = (const float*)d_in[4];
  const float* ln1_g  = (const float*)d_in[5];
  const float* ln1_b  = (const float*)d_in[6];
  const float* ln2_g  = (const float*)d_in[7];
  const float* ln2_b  = (const float*)d_in[8];
  const float* ffn_w1 = (const float*)d_in[9];
  const float* ffn_b1 = (const float*)d_in[10];
  const float* ffn_w2 = (const float*)d_in[11];
  const float* ffn_b2 = (const float*)d_in[12];

  char* ws = (char*)d_ws;
  size_t off = 0;
  auto alloc = [&](size_t bytes) -> void* {
    off = (off + 255) & ~(size_t)255;
    void* p = ws + off;
    off += bytes;
    return p;
  };
  bf16*  XB   = (bf16*) alloc((size_t)MM * DD * 2);
  bf16*  BIGB = (bf16*) alloc((size_t)MM * FF * 2);
  float* PE   = (float*)alloc((size_t)LL * DD * 4);
  bf16*  WQKV = (bf16*) alloc((size_t)NLAYERS * DD * 3 * DD * 2);
  bf16*  WFC  = (bf16*) alloc((size_t)NLAYERS * DD * DD * 2);
  bf16*  W1T  = (bf16*) alloc((size_t)NLAYERS * DD * FF * 2);
  bf16*  W2T  = (bf16*) alloc((size_t)NLAYERS * FF * DD * 2);
  bf16*  AOUT = BIGB + (size_t)MM * (3 * DD);
  float* Y    = (float*)d_out;
  (void)ws_size; (void)in_sizes; (void)n_in; (void)out_size;

  pe_kernel<<<200, 256, 0, stream>>>(PE);
  transpose_cast<<<dim3(48, 16, NLAYERS), dim3(32, 8), 0, stream>>>(qkv_w,  WQKV, 512, 1536);
  transpose_cast<<<dim3(16, 16, NLAYERS), dim3(32, 8), 0, stream>>>(fc_w,   WFC,  512, 512);
  transpose_cast<<<dim3(64, 16, NLAYERS), dim3(32, 8), 0, stream>>>(ffn_w1, W1T,  512, 2048);
  transpose_cast<<<dim3(16, 64, NLAYERS), dim3(32, 8), 0, stream>>>(ffn_w2, W2T,  2048, 512);
  x0_kernel<<<12800, 256, 0, stream>>>(x_in, PE, XB);

  for (int i = 0; i < NLAYERS; ++i) {
    // qkv = x @ qkv_w -> bf16 [M,1536]
    gemm128<1, 0><<<dim3(12, 200), 256, 0, stream>>>(
        XB, WQKV + (size_t)i * DD * 3 * DD, nullptr, BIGB, 3 * DD, DD);
    attn_mfma<<<BB * NH, 256, 0, stream>>>(BIGB, mask, AOUT);
    // attn proj + bias -> fp32 Y
    gemm128<0, 0><<<dim3(4, 200), 256, 0, stream>>>(
        AOUT, WFC + (size_t)i * DD * DD, fc_b + i * DD, Y, DD, DD);
    // x = LN(Y + x)
    ln_kernel<0><<<MM / 4, 256, 0, stream>>>(Y, XB, ln1_g + i * DD, ln1_b + i * DD, XB, nullptr);
    // h = relu(x @ w1 + b1) -> bf16 [M,2048]
    gemm128<1, 1><<<dim3(16, 200), 256, 0, stream>>>(
        XB, W1T + (size_t)i * DD * FF, ffn_b1 + i * FF, BIGB, FF, DD);
    // y = h @ w2 + b2 -> fp32 Y
    gemm128<0, 0><<<dim3(4, 200), 256, 0, stream>>>(
        BIGB, W2T + (size_t)i * FF * DD, ffn_b2 + i * DD, Y, DD, FF);
    // x = LN(Y + x); final layer also writes fp32 d_out (in place on Y rows)
    if (i == NLAYERS - 1)
      ln_kernel<1><<<MM / 4, 256, 0, stream>>>(Y, XB, ln2_g + i * DD, ln2_b + i * DD,
                                               XB, (float*)d_out);
    else
      ln_kernel<0><<<MM / 4, 256, 0, stream>>>(Y, XB, ln2_g + i * DD, ln2_b + i * DD, XB, nullptr);
  }
}